// Round 19
// baseline (371.875 us; speedup 1.0000x reference)
//
#include <hip/hip_runtime.h>
#include <hip/hip_bf16.h>
#include <math.h>

#define RR   32
#define RB   4
#define CIN  32
#define CO   64
#define NP   32768
#define SD   256
#define NVOX (RR*RR*RR)       // 32768
#define GRP  8
#define GN_CNT 262144.0f      // 8 ch * 32768 vox per group
#define PR   34               // padded resolution
#define PSLICE (PR*PR*CO)     // 73984   (U stride)
#define PROW   (PR*CO)        // 2176    (V stride)
#define PVOL   ((size_t)PR*PR*PR*CO)   // per-batch padded elems 2,515,456
#define CPB    314432         // PVOL/8: padded 8-channel chunks per batch

typedef __attribute__((ext_vector_type(8))) short short8;
typedef __attribute__((ext_vector_type(16))) float f32x16;

__device__ inline float silu_f(float x){ return x / (1.f + __expf(-x)); }
__device__ inline float bf2f(ushort u){ uint v = ((uint)u)<<16; return *(float*)&v; }
__device__ inline ushort f2bf(float x){ __hip_bfloat16 h = __float2bfloat16(x); return *(ushort*)&h; }

// direct global->LDS DMA, 16B per lane; l must be wave-uniform (dest = l + lane*16)
__device__ inline void gload_lds16(const void* g, void* l){
    __builtin_amdgcn_global_load_lds(
        (const __attribute__((address_space(1))) void*)g,
        (__attribute__((address_space(3))) void*)l,
        16, 0, 0);
}

__device__ inline void wpack_dev(const float* __restrict__ w, short* __restrict__ wp, int i){
    // bf16 [t][kc4][nt][lane][8]; B-frag: col(oc)=nt*32+(lane&31), k(ci)=kc*16+(lane>>5)*8+j
    int l  = i & 63;
    int nt = (i>>6) & 1;
    int kc = (i>>7) & 3;
    int t  = i>>9;
    int oc = nt*32 + (l&31);
    int cib = kc*16 + (l>>5)*8;
    ushort out[8];
    #pragma unroll
    for (int j=0;j<8;j++) out[j] = f2bf(w[((oc*CO + cib + j))*27 + t]);
    *(uint4*)(wp + (size_t)i*8) = *(uint4*)out;
}

// ---------------- fused prep: wpack x2 + adain + stats-zero + minmax + cnt-zero ----------------
__global__ __launch_bounds__(256) void k_prep(const float* __restrict__ w_v1, const float* __restrict__ w_v2,
                      short* __restrict__ wp1, short* __restrict__ wp2,
                      const float* __restrict__ style, const float* __restrict__ w_as,
                      const float* __restrict__ b_as, const float* __restrict__ w_ab,
                      const float* __restrict__ b_ab, float* __restrict__ ada_s,
                      float* __restrict__ ada_b, float* __restrict__ stats,
                      const float* __restrict__ coords, float* __restrict__ vmm,
                      int* __restrict__ cnt){
    __shared__ float smn[256][3], smx[256][3];
    int blk = blockIdx.x, t = threadIdx.x;
    if (blk < 54){
        int i = blk*256 + t;
        if (i < 27*4*2*64) wpack_dev(w_v1, wp1, i);
    } else if (blk < 108){
        int i = (blk-54)*256 + t;
        if (i < 27*4*2*64) wpack_dev(w_v2, wp2, i);
    } else if (blk == 108){
        stats[t] = 0.f;
        int b = t >> 6, o = t & 63;
        const float* st = style + b*SD;
        float accs = b_as[o], accb = b_ab[o];
        for (int k=0;k<SD;k++){ float sv = st[k]; accs += sv*w_as[o*SD+k]; accb += sv*w_ab[o*SD+k]; }
        ada_s[t]=accs; ada_b[t]=accb;
    } else if (blk < 113){
        int b = blk - 109;
        float mn[3]={1e30f,1e30f,1e30f}, mx[3]={-1e30f,-1e30f,-1e30f};
        const float* cp = coords + (size_t)b*NP*3;
        for (int n=t;n<NP;n+=256){
            #pragma unroll
            for(int d=0;d<3;d++){ float v = cp[n*3+d]; mn[d]=fminf(mn[d],v); mx[d]=fmaxf(mx[d],v);}
        }
        #pragma unroll
        for(int d=0;d<3;d++){ smn[t][d]=mn[d]; smx[t][d]=mx[d]; }
        __syncthreads();
        for(int s=128;s>0;s>>=1){
            if(t<s){
                #pragma unroll
                for(int d=0;d<3;d++){
                    smn[t][d]=fminf(smn[t][d],smn[t+s][d]);
                    smx[t][d]=fmaxf(smx[t][d],smx[t+s][d]);
                }
            }
            __syncthreads();
        }
        if(t<3){ vmm[b*6+t]=smn[0][t]; vmm[b*6+3+t]=smx[0][t]; }
    } else {
        cnt[(blk-113)*256 + t] = 0;
    }
}

// ---------------- voxel id + count + store clamped normalized coords ----------------
__global__ __launch_bounds__(256) void k_count(const float* __restrict__ coords, const float* __restrict__ vmm,
                        int* __restrict__ pid, int* __restrict__ cnt, float4* __restrict__ nrm){
    int p = blockIdx.x*256 + threadIdx.x;
    int b = p >> 15, n = p & (NP-1);
    const float* cp = coords + (size_t)(b*NP + n)*3;
    int id[3];
    float nc[3];
    #pragma unroll
    for(int d=0;d<3;d++){
        float vmin = vmm[b*6+d], vmax = vmm[b*6+3+d];
        float nr = (cp[d]-vmin)/fmaxf(vmax-vmin,1e-8f)*(RR-1);
        nc[d] = fminf(fmaxf(nr,0.f),(float)(RR-1));
        int ii = (int)rintf(nr);
        id[d] = min(max(ii,0),RR-1);
    }
    int flat = (id[0]*RR + id[1])*RR + id[2];
    pid[p] = flat;
    nrm[p] = make_float4(nc[0],nc[1],nc[2],0.f);
    atomicAdd(&cnt[(b<<15)+flat], 1);
}

// ---------------- per-batch exclusive scan of 32768 counts ----------------
__global__ __launch_bounds__(1024) void k_scan(const int* __restrict__ cnt, int* __restrict__ offs,
                        int* __restrict__ cursor){
    int b = blockIdx.x, t = threadIdx.x;
    const int* c = cnt + (b<<15);
    int base = t*32;
    int pref[32];
    int s = 0;
    #pragma unroll
    for (int k4=0;k4<8;k4++){
        int4 q = *(const int4*)(c + base + k4*4);
        pref[k4*4+0]=s; s+=q.x;
        pref[k4*4+1]=s; s+=q.y;
        pref[k4*4+2]=s; s+=q.z;
        pref[k4*4+3]=s; s+=q.w;
    }
    int lane = t & 63, w = t >> 6;
    int inc = s;
    #pragma unroll
    for (int off=1; off<64; off<<=1){ int u = __shfl_up(inc, off); if (lane>=off) inc += u; }
    __shared__ int wsum[16];
    if (lane==63) wsum[w]=inc;
    __syncthreads();
    int wexcl=0;
    for (int i=0;i<w;i++) wexcl += wsum[i];
    int texcl = wexcl + inc - s;
    int* o = offs + (b<<15) + base;
    int* cu = cursor + (b<<15) + base;
    #pragma unroll
    for (int k=0;k<32;k++){ int v = texcl + pref[k]; o[k]=v; cu[k]=v; }
}

// ---------------- point_in conv1x1 via MFMA + inline FILL (slot assign + nrm scatter) ----------------
__global__ __launch_bounds__(256) void k_pin(const float* __restrict__ feats, const float* __restrict__ w_pin,
                      const int* __restrict__ pid, int* __restrict__ cursor,
                      int* __restrict__ slotmap, const float4* __restrict__ nrm,
                      float4* __restrict__ nrm_s,
                      ushort* __restrict__ ybuf, float* __restrict__ stats){
    __shared__ float sred[GRP*2];
    int t = threadIdx.x;
    if (t<GRP*2) sred[t]=0.f;
    __syncthreads();
    int l = t & 63, wv = t >> 6;
    int lc = l & 31, h = l >> 5;
    int p = blockIdx.x*128 + wv*32 + lc;
    int b = p >> 15, n = p & (NP-1);
    int slot;
    if (h==0){
        int v = pid[p];
        slot = atomicAdd(&cursor[(b<<15)+v], 1);
        slotmap[p] = slot;
        nrm_s[(b<<15)+slot] = nrm[p];
    }
    slot = __shfl(slot, lc, 64);
    short8 aw[2][2];
    #pragma unroll
    for (int nt=0;nt<2;nt++)
    #pragma unroll
    for (int kc=0;kc<2;kc++){
        ushort tmp[8];
        #pragma unroll
        for (int j=0;j<8;j++) tmp[j]=f2bf(w_pin[(nt*32+lc)*CIN + kc*16 + h*8 + j]);
        aw[nt][kc]=*(short8*)tmp;
    }
    const float* fp = feats + (size_t)b*CIN*NP + n;
    short8 bf[2];
    #pragma unroll
    for (int kc=0;kc<2;kc++){
        ushort tmp[8];
        #pragma unroll
        for (int j=0;j<8;j++) tmp[j]=f2bf(fp[(size_t)(kc*16+h*8+j)*NP]);
        bf[kc]=*(short8*)tmp;
    }
    f32x16 acc0={}, acc1={};
    #pragma unroll
    for (int kc=0;kc<2;kc++){
        acc0 = __builtin_amdgcn_mfma_f32_32x32x16_bf16(aw[0][kc], bf[kc], acc0, 0,0,0);
        acc1 = __builtin_amdgcn_mfma_f32_32x32x16_bf16(aw[1][kc], bf[kc], acc1, 0,0,0);
    }
    ushort* yo = ybuf + ((size_t)(b<<15) + slot)*CO;
    float sg[8], qg[8];
    #pragma unroll
    for (int nt=0;nt<2;nt++){
        #pragma unroll
        for (int q=0;q<4;q++){
            ushort pk[4]; float s=0.f, qq=0.f;
            #pragma unroll
            for (int j=0;j<4;j++){
                float v = nt ? acc1[q*4+j] : acc0[q*4+j];
                pk[j]=f2bf(v); s+=v; qq+=v*v;
            }
            *(uint2*)(yo + nt*32 + q*8 + h*4) = *(uint2*)pk;
            sg[nt*4+q]=s; qg[nt*4+q]=qq;
        }
    }
    #pragma unroll
    for (int g=0;g<8;g++){
        float s=sg[g], q=qg[g];
        #pragma unroll
        for (int off=1; off<64; off<<=1){ s+=__shfl_xor(s,off); q+=__shfl_xor(q,off); }
        if (l==0){ atomicAdd(&sred[g*2],s); atomicAdd(&sred[g*2+1],q); }
    }
    __syncthreads();
    if (t<GRP){ atomicAdd(&stats[(b*GRP+t)*2], sred[t*2]); atomicAdd(&stats[(b*GRP+t)*2+1], sred[t*2+1]); }
}

// ---------------- gather per voxel over FULL padded volume (borders -> zero) ----------------
__global__ __launch_bounds__(256) void k_gather_pad(const ushort* __restrict__ ybuf, const int* __restrict__ offs,
                             const float* __restrict__ stats,
                             const float* __restrict__ gamma, const float* __restrict__ beta,
                             ushort* __restrict__ P){
    int i = blockIdx.x*256 + threadIdx.x;   // RB*CPB
    int b = i / CPB;
    int r = i - b*CPB;
    ushort* dst = P + (size_t)b*PVOL + (size_t)r*8;
    int pvox = r >> 3, c8 = r & 7;
    int pu = pvox / (PR*PR);
    int rem = pvox - pu*PR*PR;
    int pv = rem / PR;
    int pw = rem - pv*PR;
    if (pu==0 || pu==PR-1 || pv==0 || pv==PR-1 || pw==0 || pw==PR-1){
        uint4 z = {0,0,0,0};
        *(uint4*)dst = z;
        return;
    }
    int vox = ((pu-1)*RR + (pv-1))*RR + (pw-1);
    float s = stats[(b*GRP+c8)*2], qq = stats[(b*GRP+c8)*2+1];
    float m = s/GN_CNT;
    float inv = rsqrtf(qq/GN_CNT - m*m + 1e-5f);
    float ga[8], be[8];
    #pragma unroll
    for (int k=0;k<8;k++){ ga[k]=gamma[c8*8+k]*inv; be[k]=beta[c8*8+k]-m*ga[k]; }
    int o0 = offs[(b<<15)+vox];
    int o1 = (vox==NVOX-1) ? NP : offs[(b<<15)+vox+1];
    float acc[8];
    #pragma unroll
    for (int k=0;k<8;k++) acc[k]=0.f;
    for (int j=o0; j<o1; j++){
        uint4 raw = *(const uint4*)(ybuf + ((size_t)((b<<15)+j))*CO + c8*8);
        ushort* us = (ushort*)&raw;
        #pragma unroll
        for (int k=0;k<8;k++){
            float x = bf2f(us[k])*ga[k] + be[k];
            acc[k] += silu_f(x);
        }
    }
    float rc = (o1>o0) ? 1.f/(float)(o1-o0) : 0.f;
    ushort out[8];
    #pragma unroll
    for (int k=0;k<8;k++) out[k]=f2bf(acc[k]*rc);
    *(uint4*)dst = *(uint4*)out;
}

// ---------------- conv1: MFMA conv3d from padded Pvol; act+weights via global_load_lds ----------------
// Act LDS is linear in chunk index (dst = c*16) because the XOR swizzle is applied to the
// SOURCE chunk (src_c8 = c8 ^ (vx&7), involution within the row) -- m173 pattern.
__global__ __launch_bounds__(256, 2) void k_conv1(const ushort* __restrict__ P,
                        const short* __restrict__ wpack,
                        ushort* __restrict__ outv, float* __restrict__ stats){
    __shared__ __align__(16) char lds[10*4352 + 24576];   // 43520 act + 24576 w = 68096 B
    char* wlds = lds + 10*4352;
    int t = threadIdx.x;
    int blk = blockIdx.x;                 // ((b*32+u)*4 + vt)
    int vt = blk & 3;
    int u  = (blk >> 2) & 31;
    int b  = blk >> 7;
    int v0 = vt*8;

    int l  = t & 63;
    int wv = t >> 6;
    int lr = l & 31;
    int lh = l >> 5;

    f32x16 acc00 = {}, acc01 = {}, acc10 = {}, acc11 = {};

    for (int dz = 0; dz < 3; dz++){
        // ---- act staging: 2720 chunks, per-wave 64-chunk groups, direct-to-LDS ----
        const ushort* Pb = P + (size_t)b*PVOL + (size_t)(u+dz)*PSLICE;
        #pragma unroll
        for (int i = 0; i < 11; i++){
            int grp = i*4 + wv;
            int c = grp*64 + l;
            if (c < 2720){
                int r = c / 272;
                int ch = c - r*272;
                int vx = ch >> 3;
                int c8 = ch & 7;
                int sc8 = c8 ^ (vx & 7);
                const ushort* src = Pb + (size_t)(v0+r)*PROW + vx*64 + sc8*8;
                gload_lds16(src, lds + (size_t)grp*1024);
            }
        }
        for (int dy = 0; dy < 3; dy++){
            // ---- weight staging: 1536 uint4, per-wave groups, direct-to-LDS ----
            const uint4* wsrc = (const uint4*)(wpack + (size_t)(dz*9 + dy*3)*4096);
            #pragma unroll
            for (int i=0;i<6;i++){
                int g = i*256 + wv*64;
                gload_lds16(wsrc + g + l, wlds + (size_t)g*16);
            }
            __syncthreads();
            __builtin_amdgcn_s_setprio(1);
            #pragma unroll
            for (int dx = 0; dx < 3; dx++){
                int vx = lr + dx;
                int sw = (vx & 7) << 4;
                int ra = (2*wv + dy)*4352 + vx*128;
                int wb = dx*8192 + l*16;
                #pragma unroll
                for (int kc = 0; kc < 4; kc++){
                    short8 bw0 = *(const short8*)(wlds + wb + kc*2048);
                    short8 bw1 = *(const short8*)(wlds + wb + kc*2048 + 1024);
                    int col = (kc*32 + lh*16) ^ sw;
                    short8 av0 = *(const short8*)(lds + ra + col);
                    short8 av1 = *(const short8*)(lds + ra + 4352 + col);
                    acc00 = __builtin_amdgcn_mfma_f32_32x32x16_bf16(av0, bw0, acc00, 0, 0, 0);
                    acc01 = __builtin_amdgcn_mfma_f32_32x32x16_bf16(av0, bw1, acc01, 0, 0, 0);
                    acc10 = __builtin_amdgcn_mfma_f32_32x32x16_bf16(av1, bw0, acc10, 0, 0, 0);
                    acc11 = __builtin_amdgcn_mfma_f32_32x32x16_bf16(av1, bw1, acc11, 0, 0, 0);
                }
            }
            __builtin_amdgcn_s_setprio(0);
            __syncthreads();
        }
    }

    ushort* ob = outv;
    float s0 = 0.f, q0 = 0.f, s1 = 0.f, q1 = 0.f;
    size_t vrow0 = ((size_t)(b*32 + u)*32 + v0 + 2*wv);
    #pragma unroll
    for (int reg = 0; reg < 16; reg++){
        int x = (reg&3) + 8*(reg>>2) + 4*lh;
        float a, c;
        a = acc00[reg]; c = acc01[reg];
        s0 += a; q0 += a*a; s1 += c; q1 += c*c;
        ob[(vrow0*32 + x)*CO + lr]      = f2bf(a);
        ob[(vrow0*32 + x)*CO + 32 + lr] = f2bf(c);
        a = acc10[reg]; c = acc11[reg];
        s0 += a; q0 += a*a; s1 += c; q1 += c*c;
        ob[((vrow0+1)*32 + x)*CO + lr]      = f2bf(a);
        ob[((vrow0+1)*32 + x)*CO + 32 + lr] = f2bf(c);
    }
    #pragma unroll
    for (int off : {1,2,4,32}){
        s0 += __shfl_xor(s0, off); q0 += __shfl_xor(q0, off);
        s1 += __shfl_xor(s1, off); q1 += __shfl_xor(q1, off);
    }
    if (lh==0 && (lr&7)==0){
        int g0 = lr>>3;
        atomicAdd(&stats[(b*GRP+g0)*2],     s0);
        atomicAdd(&stats[(b*GRP+g0)*2+1],   q0);
        atomicAdd(&stats[(b*GRP+4+g0)*2],   s1);
        atomicAdd(&stats[(b*GRP+4+g0)*2+1], q1);
    }
}

// ---------------- conv2: GN(st1)+SiLU fused into staging; weights via global_load_lds ----------------
__global__ __launch_bounds__(256, 2) void k_conv2(const ushort* __restrict__ in,
                        const short* __restrict__ wpack,
                        const float* __restrict__ gst, const float* __restrict__ gg,
                        const float* __restrict__ gb,
                        ushort* __restrict__ outv, float* __restrict__ stats){
    __shared__ __align__(16) char lds[10*4352 + 24576];
    char* wlds = lds + 10*4352;
    int t = threadIdx.x;
    int blk = blockIdx.x;
    int vt = blk & 3;
    int u  = (blk >> 2) & 31;
    int b  = blk >> 7;
    int v0 = vt*8;

    int l  = t & 63;
    int wv = t >> 6;
    int lr = l & 31;
    int lh = l >> 5;

    float gm[8], gi[8];
    #pragma unroll
    for (int g=0; g<8; g++){
        float m = gst[(b*GRP+g)*2]/GN_CNT;
        gm[g] = m;
        gi[g] = rsqrtf(gst[(b*GRP+g)*2+1]/GN_CNT - m*m + 1e-5f);
    }

    f32x16 acc00 = {}, acc01 = {}, acc10 = {}, acc11 = {};

    for (int dz = 0; dz < 3; dz++){
        for (int i = t; i < 2720; i += 256){
            int r = i / 272;
            int chunk = i - r*272;
            int vx = chunk >> 3;
            int c8 = chunk & 7;
            uint4 val = make_uint4(0,0,0,0);
            int au = u + dz - 1, av = v0 + r - 1, ax = vx - 1;
            if ((unsigned)au < 32u && (unsigned)av < 32u && (unsigned)ax < 32u){
                uint4 rv = *(const uint4*)(in + ((size_t)(((b*32+au)*32+av)*32+ax))*CO + c8*8);
                float m = gm[c8], iv = gi[c8];
                ushort* us = (ushort*)&rv;
                ushort o8[8];
                #pragma unroll
                for (int j=0;j<8;j++){
                    int c = c8*8+j;
                    float x = (bf2f(us[j]) - m)*iv*gg[c] + gb[c];
                    o8[j] = f2bf(silu_f(x));
                }
                val = *(uint4*)o8;
            }
            *(uint4*)(lds + r*4352 + vx*128 + ((c8<<4) ^ ((vx&7)<<4))) = val;
        }
        for (int dy = 0; dy < 3; dy++){
            const uint4* wsrc = (const uint4*)(wpack + (size_t)(dz*9 + dy*3)*4096);
            #pragma unroll
            for (int i=0;i<6;i++){
                int g = i*256 + wv*64;
                gload_lds16(wsrc + g + l, wlds + (size_t)g*16);
            }
            __syncthreads();
            __builtin_amdgcn_s_setprio(1);
            #pragma unroll
            for (int dx = 0; dx < 3; dx++){
                int vx = lr + dx;
                int sw = (vx & 7) << 4;
                int ra = (2*wv + dy)*4352 + vx*128;
                int wb = dx*8192 + l*16;
                #pragma unroll
                for (int kc = 0; kc < 4; kc++){
                    short8 bw0 = *(const short8*)(wlds + wb + kc*2048);
                    short8 bw1 = *(const short8*)(wlds + wb + kc*2048 + 1024);
                    int col = (kc*32 + lh*16) ^ sw;
                    short8 av0 = *(const short8*)(lds + ra + col);
                    short8 av1 = *(const short8*)(lds + ra + 4352 + col);
                    acc00 = __builtin_amdgcn_mfma_f32_32x32x16_bf16(av0, bw0, acc00, 0, 0, 0);
                    acc01 = __builtin_amdgcn_mfma_f32_32x32x16_bf16(av0, bw1, acc01, 0, 0, 0);
                    acc10 = __builtin_amdgcn_mfma_f32_32x32x16_bf16(av1, bw0, acc10, 0, 0, 0);
                    acc11 = __builtin_amdgcn_mfma_f32_32x32x16_bf16(av1, bw1, acc11, 0, 0, 0);
                }
            }
            __builtin_amdgcn_s_setprio(0);
            __syncthreads();
        }
    }

    ushort* ob = outv;
    float s0 = 0.f, q0 = 0.f, s1 = 0.f, q1 = 0.f;
    size_t vrow0 = ((size_t)(b*32 + u)*32 + v0 + 2*wv);
    #pragma unroll
    for (int reg = 0; reg < 16; reg++){
        int x = (reg&3) + 8*(reg>>2) + 4*lh;
        float a, c;
        a = acc00[reg]; c = acc01[reg];
        s0 += a; q0 += a*a; s1 += c; q1 += c*c;
        ob[(vrow0*32 + x)*CO + lr]      = f2bf(a);
        ob[(vrow0*32 + x)*CO + 32 + lr] = f2bf(c);
        a = acc10[reg]; c = acc11[reg];
        s0 += a; q0 += a*a; s1 += c; q1 += c*c;
        ob[((vrow0+1)*32 + x)*CO + lr]      = f2bf(a);
        ob[((vrow0+1)*32 + x)*CO + 32 + lr] = f2bf(c);
    }
    #pragma unroll
    for (int off : {1,2,4,32}){
        s0 += __shfl_xor(s0, off); q0 += __shfl_xor(q0, off);
        s1 += __shfl_xor(s1, off); q1 += __shfl_xor(q1, off);
    }
    if (lh==0 && (lr&7)==0){
        int g0 = lr>>3;
        atomicAdd(&stats[(b*GRP+g0)*2],     s0);
        atomicAdd(&stats[(b*GRP+g0)*2+1],   q0);
        atomicAdd(&stats[(b*GRP+4+g0)*2],   s1);
        atomicAdd(&stats[(b*GRP+4+g0)*2+1], q1);
    }
}

// ---------------- devoxelize in CSR-SORTED order (+fused GN+SiLU of conv2) + fuse conv1x1 + stats ----------------
__global__ __launch_bounds__(256) void k_devox_fuse(const ushort* __restrict__ vox_,
                             const float4* __restrict__ nrm_s, const float* __restrict__ wf,
                             const float* __restrict__ st2, const float* __restrict__ g_v2,
                             const float* __restrict__ b_v2,
                             ushort* __restrict__ obuf, float* __restrict__ stats){
    __shared__ float sred[GRP*2];
    int t = threadIdx.x;
    if (t<GRP*2) sred[t]=0.f;
    __syncthreads();
    int l = t & 63, wv = t >> 6;
    int lc = l & 31, h = l >> 5;
    int j_ = blockIdx.x*128 + wv*32 + lc;      // sorted slot index
    int b = j_ >> 15;
    short8 aw[2][4];
    #pragma unroll
    for (int nt=0;nt<2;nt++)
    #pragma unroll
    for (int kc=0;kc<4;kc++){
        ushort tmp[8];
        #pragma unroll
        for (int j=0;j<8;j++) tmp[j]=f2bf(wf[(nt*32+lc)*CO + kc*16 + h*8 + j]);
        aw[nt][kc]=*(short8*)tmp;
    }
    float ga[4][8], be[4][8];
    #pragma unroll
    for (int kc=0;kc<4;kc++){
        int g = kc*2 + h;
        float s = st2[(b*GRP+g)*2], qq = st2[(b*GRP+g)*2+1];
        float m = s/GN_CNT;
        float inv = rsqrtf(qq/GN_CNT - m*m + 1e-5f);
        #pragma unroll
        for (int j=0;j<8;j++){
            int c = kc*16 + h*8 + j;
            ga[kc][j] = g_v2[c]*inv;
            be[kc][j] = b_v2[c] - m*ga[kc][j];
        }
    }
    float4 nr4 = nrm_s[j_];
    float f3[3] = {nr4.x, nr4.y, nr4.z};
    float fr[3]; int x0[3];
    #pragma unroll
    for(int d=0;d<3;d++){
        float fl = floorf(f3[d]);
        x0[d]=(int)fl; fr[d]=f3[d]-fl;
    }
    float dev[4][8] = {};
    const ushort* vb = vox_ + (size_t)b*NVOX*CO;
    #pragma unroll
    for (int k=0;k<8;k++){
        int d0=(k>>2)&1, d1=(k>>1)&1, d2=k&1;
        int i0=min(x0[0]+d0,RR-1), i1=min(x0[1]+d1,RR-1), i2=min(x0[2]+d2,RR-1);
        float w = (d0?fr[0]:1.f-fr[0])*(d1?fr[1]:1.f-fr[1])*(d2?fr[2]:1.f-fr[2]);
        const ushort* vp = vb + (size_t)((i0*RR+i1)*RR+i2)*CO + h*8;
        #pragma unroll
        for (int kc=0;kc<4;kc++){
            uint4 rv = *(const uint4*)(vp + kc*16);
            ushort* us = (ushort*)&rv;
            #pragma unroll
            for (int j=0;j<8;j++){
                float x = bf2f(us[j])*ga[kc][j] + be[kc][j];
                dev[kc][j] += w * silu_f(x);
            }
        }
    }
    short8 bf[4];
    #pragma unroll
    for (int kc=0;kc<4;kc++){
        ushort tmp[8];
        #pragma unroll
        for (int j=0;j<8;j++) tmp[j]=f2bf(dev[kc][j]);
        bf[kc]=*(short8*)tmp;
    }
    f32x16 acc0={}, acc1={};
    #pragma unroll
    for (int kc=0;kc<4;kc++){
        acc0 = __builtin_amdgcn_mfma_f32_32x32x16_bf16(aw[0][kc], bf[kc], acc0, 0,0,0);
        acc1 = __builtin_amdgcn_mfma_f32_32x32x16_bf16(aw[1][kc], bf[kc], acc1, 0,0,0);
    }
    ushort* op = obuf + (size_t)j_*CO;
    float sg[8], qg[8];
    #pragma unroll
    for (int nt=0;nt<2;nt++){
        #pragma unroll
        for (int q=0;q<4;q++){
            ushort pk[4]; float s=0.f, qq=0.f;
            #pragma unroll
            for (int j=0;j<4;j++){
                float v = nt ? acc1[q*4+j] : acc0[q*4+j];
                pk[j]=f2bf(v); s+=v; qq+=v*v;
            }
            *(uint2*)(op + nt*32 + q*8 + h*4) = *(uint2*)pk;
            sg[nt*4+q]=s; qg[nt*4+q]=qq;
        }
    }
    #pragma unroll
    for (int g=0;g<8;g++){
        float s=sg[g], q=qg[g];
        #pragma unroll
        for (int off=1; off<64; off<<=1){ s+=__shfl_xor(s,off); q+=__shfl_xor(q,off); }
        if (l==0){ atomicAdd(&sred[g*2],s); atomicAdd(&sred[g*2+1],q); }
    }
    __syncthreads();
    if (t<GRP){ atomicAdd(&stats[(b*GRP+t)*2], sred[t*2]); atomicAdd(&stats[(b*GRP+t)*2+1], sred[t*2+1]); }
}

// ---------------- final: GN+SiLU + MFMA skip conv + AdaIN, write (B,C,N) ----------------
__global__ __launch_bounds__(256) void k_final(const ushort* __restrict__ obuf, const int* __restrict__ slotmap,
                        const float* __restrict__ stats,
                        const float* __restrict__ gamma, const float* __restrict__ beta,
                        const float* __restrict__ feats, const float* __restrict__ wskip,
                        const float* __restrict__ ada_s, const float* __restrict__ ada_b,
                        float* __restrict__ out){
    int t = threadIdx.x;
    int l = t & 63, wv = t >> 6;
    int lc = l & 31, h = l >> 5;
    int p = blockIdx.x*128 + wv*32 + lc;
    int b = p >> 15, n = p & (NP-1);
    short8 aw[2][2];
    #pragma unroll
    for (int nt=0;nt<2;nt++)
    #pragma unroll
    for (int kc=0;kc<2;kc++){
        ushort tmp[8];
        #pragma unroll
        for (int j=0;j<8;j++) tmp[j]=f2bf(wskip[(nt*32+lc)*CIN + kc*16 + h*8 + j]);
        aw[nt][kc]=*(short8*)tmp;
    }
    const float* fp = feats + (size_t)b*CIN*NP + n;
    short8 bf[2];
    #pragma unroll
    for (int kc=0;kc<2;kc++){
        ushort tmp[8];
        #pragma unroll
        for (int j=0;j<8;j++) tmp[j]=f2bf(fp[(size_t)(kc*16+h*8+j)*NP]);
        bf[kc]=*(short8*)tmp;
    }
    f32x16 acc0={}, acc1={};
    #pragma unroll
    for (int kc=0;kc<2;kc++){
        acc0 = __builtin_amdgcn_mfma_f32_32x32x16_bf16(aw[0][kc], bf[kc], acc0, 0,0,0);
        acc1 = __builtin_amdgcn_mfma_f32_32x32x16_bf16(aw[1][kc], bf[kc], acc1, 0,0,0);
    }
    float mean[GRP], inv[GRP];
    #pragma unroll
    for (int g=0; g<GRP; g++){
        float s=stats[(b*GRP+g)*2], q=stats[(b*GRP+g)*2+1];
        float m=s/GN_CNT;
        mean[g]=m; inv[g]=rsqrtf(q/GN_CNT - m*m + 1e-5f);
    }
    int slot = slotmap[p];
    const ushort* ip = obuf + ((size_t)(b<<15) + slot)*CO;
    float* op = out + (size_t)b*CO*NP + n;
    #pragma unroll
    for (int nt=0;nt<2;nt++){
        #pragma unroll
        for (int q=0;q<4;q++){
            uint2 raw = *(const uint2*)(ip + nt*32 + q*8 + h*4);
            ushort* us = (ushort*)&raw;
            int g = nt*4 + q;
            #pragma unroll
            for (int j=0;j<4;j++){
                int oc = nt*32 + q*8 + h*4 + j;
                float u = (bf2f(us[j]) - mean[g])*inv[g]*gamma[oc] + beta[oc];
                u = silu_f(u);
                float sk = nt ? acc1[q*4+j] : acc0[q*4+j];
                float s = ada_s[b*CO+oc], bb = ada_b[b*CO+oc];
                op[(size_t)oc*NP] = (u+sk)*(1.f+s)+bb;
            }
        }
    }
}

extern "C" void kernel_launch(void* const* d_in, const int* in_sizes, int n_in,
                              void* d_out, int out_size, void* d_ws, size_t ws_size,
                              hipStream_t stream){
    const float* feats =(const float*)d_in[0];
    const float* coords=(const float*)d_in[1];
    const float* style =(const float*)d_in[2];
    const float* w_pin =(const float*)d_in[3];
    const float* g_pin =(const float*)d_in[4];
    const float* b_pin =(const float*)d_in[5];
    const float* w_v1  =(const float*)d_in[6];
    const float* g_v1  =(const float*)d_in[7];
    const float* b_v1  =(const float*)d_in[8];
    const float* w_v2  =(const float*)d_in[9];
    const float* g_v2  =(const float*)d_in[10];
    const float* b_v2  =(const float*)d_in[11];
    const float* w_fuse=(const float*)d_in[12];
    const float* g_f   =(const float*)d_in[13];
    const float* b_f   =(const float*)d_in[14];
    const float* w_skip=(const float*)d_in[15];
    const float* w_as  =(const float*)d_in[16];
    const float* b_as  =(const float*)d_in[17];
    const float* w_ab  =(const float*)d_in[18];
    const float* b_ab  =(const float*)d_in[19];
    float* out=(float*)d_out;
    char* ws =(char*)d_ws;

    // workspace layout (bytes)
    ushort* ybuf  = (ushort*)ws;                            // 16.7 MB (aliased later by obuf)
    ushort* Pvol  = (ushort*)(ws + 16777216);               // 20.1 MB (reused as conv2 out)
    ushort* raw   = (ushort*)(ws + 16777216 + 20123648);    // 16.7 MB
    char*   small = ws + 16777216 + 20123648 + 16777216;
    float* stats  = (float*)small;                          // 256 floats
    float* vmm    = stats + 256;                            // 24
    float* ada_s  = vmm + 24;                               // 256
    float* ada_b  = ada_s + RB*CO;                          // 256
    short* wp1    = (short*)(ada_b + RB*CO);                // 110592 shorts
    short* wp2    = wp1 + 27*4*2*64*8;                      // 110592 shorts
    int*   pid    = (int*)(wp2 + 27*4*2*64*8);              // RB*NP
    int*   cnt    = pid + RB*NP;                            // RB*NVOX
    int*   offs   = cnt + RB*NVOX;                          // RB*NVOX
    int*   cursor = offs + RB*NVOX;                         // RB*NVOX
    int*   slotmap= cursor + RB*NVOX;                       // RB*NP
    float4* nrm4  = (float4*)(slotmap + RB*NP);             // RB*NP float4
    float4* nrm_s = nrm4 + RB*NP;                           // RB*NP float4
    ushort* vox2  = Pvol;                                   // conv2 output (unpadded 16.7 MB)
    ushort* obuf  = ybuf;                                   // reuse after gather

    float* st0 = stats;
    float* st1 = stats + 64;
    float* st2 = stats + 128;
    float* st3 = stats + 192;

    k_prep<<<625,256,0,stream>>>(w_v1,w_v2,wp1,wp2,style,w_as,b_as,w_ab,b_ab,
                                 ada_s,ada_b,stats,coords,vmm,cnt);
    k_count<<<RB*NP/256,256,0,stream>>>(coords,vmm,pid,cnt,nrm4);
    k_scan<<<RB,1024,0,stream>>>(cnt,offs,cursor);
    k_pin<<<RB*NP/128,256,0,stream>>>(feats,w_pin,pid,cursor,slotmap,nrm4,nrm_s,ybuf,st0);
    k_gather_pad<<<RB*CPB/256,256,0,stream>>>(ybuf,offs,st0,g_pin,b_pin,Pvol);

    k_conv1<<<RB*RR*4,256,0,stream>>>(Pvol, wp1, raw, st1);
    k_conv2<<<RB*RR*4,256,0,stream>>>(raw, wp2, st1, g_v1, b_v1, vox2, st2);

    k_devox_fuse<<<RB*NP/128,256,0,stream>>>(vox2, nrm_s, w_fuse,
                                             st2, g_v2, b_v2, obuf, st3);
    k_final<<<RB*NP/128,256,0,stream>>>(obuf, slotmap, st3, g_f, b_f, feats, w_skip, ada_s, ada_b, out);
}

// Round 20
// 367.653 us; speedup vs baseline: 1.0115x; 1.0115x over previous
//
#include <hip/hip_runtime.h>
#include <hip/hip_bf16.h>
#include <math.h>

#define RR   32
#define RB   4
#define CIN  32
#define CO   64
#define NP   32768
#define SD   256
#define NVOX (RR*RR*RR)       // 32768
#define GRP  8
#define GN_CNT 262144.0f      // 8 ch * 32768 vox per group
#define PR   34               // padded resolution
#define PSLICE (PR*PR*CO)     // 73984   (U stride)
#define PROW   (PR*CO)        // 2176    (V stride)
#define PVOL   ((size_t)PR*PR*PR*CO)   // per-batch padded elems 2,515,456
#define CPB    314432         // PVOL/8: padded 8-channel chunks per batch

typedef __attribute__((ext_vector_type(8))) short short8;
typedef __attribute__((ext_vector_type(16))) float f32x16;

__device__ inline float silu_f(float x){ return x / (1.f + __expf(-x)); }
__device__ inline float bf2f(ushort u){ uint v = ((uint)u)<<16; return *(float*)&v; }
__device__ inline ushort f2bf(float x){ __hip_bfloat16 h = __float2bfloat16(x); return *(ushort*)&h; }

__device__ inline void wpack_dev(const float* __restrict__ w, short* __restrict__ wp, int i){
    // bf16 [t][kc4][nt][lane][8]; B-frag: col(oc)=nt*32+(lane&31), k(ci)=kc*16+(lane>>5)*8+j
    int l  = i & 63;
    int nt = (i>>6) & 1;
    int kc = (i>>7) & 3;
    int t  = i>>9;
    int oc = nt*32 + (l&31);
    int cib = kc*16 + (l>>5)*8;
    ushort out[8];
    #pragma unroll
    for (int j=0;j<8;j++) out[j] = f2bf(w[((oc*CO + cib + j))*27 + t]);
    *(uint4*)(wp + (size_t)i*8) = *(uint4*)out;
}

// ---------------- fused prep: wpack x2 + adain + stats-zero + minmax + cnt-zero ----------------
__global__ __launch_bounds__(256) void k_prep(const float* __restrict__ w_v1, const float* __restrict__ w_v2,
                      short* __restrict__ wp1, short* __restrict__ wp2,
                      const float* __restrict__ style, const float* __restrict__ w_as,
                      const float* __restrict__ b_as, const float* __restrict__ w_ab,
                      const float* __restrict__ b_ab, float* __restrict__ ada_s,
                      float* __restrict__ ada_b, float* __restrict__ stats,
                      const float* __restrict__ coords, float* __restrict__ vmm,
                      int* __restrict__ cnt){
    __shared__ float smn[256][3], smx[256][3];
    int blk = blockIdx.x, t = threadIdx.x;
    if (blk < 54){
        int i = blk*256 + t;
        if (i < 27*4*2*64) wpack_dev(w_v1, wp1, i);
    } else if (blk < 108){
        int i = (blk-54)*256 + t;
        if (i < 27*4*2*64) wpack_dev(w_v2, wp2, i);
    } else if (blk == 108){
        stats[t] = 0.f;
        int b = t >> 6, o = t & 63;
        const float* st = style + b*SD;
        float accs = b_as[o], accb = b_ab[o];
        for (int k=0;k<SD;k++){ float sv = st[k]; accs += sv*w_as[o*SD+k]; accb += sv*w_ab[o*SD+k]; }
        ada_s[t]=accs; ada_b[t]=accb;
    } else if (blk < 113){
        int b = blk - 109;
        float mn[3]={1e30f,1e30f,1e30f}, mx[3]={-1e30f,-1e30f,-1e30f};
        const float* cp = coords + (size_t)b*NP*3;
        for (int n=t;n<NP;n+=256){
            #pragma unroll
            for(int d=0;d<3;d++){ float v = cp[n*3+d]; mn[d]=fminf(mn[d],v); mx[d]=fmaxf(mx[d],v);}
        }
        #pragma unroll
        for(int d=0;d<3;d++){ smn[t][d]=mn[d]; smx[t][d]=mx[d]; }
        __syncthreads();
        for(int s=128;s>0;s>>=1){
            if(t<s){
                #pragma unroll
                for(int d=0;d<3;d++){
                    smn[t][d]=fminf(smn[t][d],smn[t+s][d]);
                    smx[t][d]=fmaxf(smx[t][d],smx[t+s][d]);
                }
            }
            __syncthreads();
        }
        if(t<3){ vmm[b*6+t]=smn[0][t]; vmm[b*6+3+t]=smx[0][t]; }
    } else {
        // zero cnt: blocks 113..624 cover RB*NVOX ints
        cnt[(blk-113)*256 + t] = 0;
    }
}

// ---------------- voxel id + count + store clamped normalized coords ----------------
__global__ __launch_bounds__(256) void k_count(const float* __restrict__ coords, const float* __restrict__ vmm,
                        int* __restrict__ pid, int* __restrict__ cnt, float4* __restrict__ nrm){
    int p = blockIdx.x*256 + threadIdx.x;
    int b = p >> 15, n = p & (NP-1);
    const float* cp = coords + (size_t)(b*NP + n)*3;
    int id[3];
    float nc[3];
    #pragma unroll
    for(int d=0;d<3;d++){
        float vmin = vmm[b*6+d], vmax = vmm[b*6+3+d];
        float nr = (cp[d]-vmin)/fmaxf(vmax-vmin,1e-8f)*(RR-1);
        nc[d] = fminf(fmaxf(nr,0.f),(float)(RR-1));
        int ii = (int)rintf(nr);
        id[d] = min(max(ii,0),RR-1);
    }
    int flat = (id[0]*RR + id[1])*RR + id[2];
    pid[p] = flat;
    nrm[p] = make_float4(nc[0],nc[1],nc[2],0.f);
    atomicAdd(&cnt[(b<<15)+flat], 1);
}

// ---------------- per-batch exclusive scan of 32768 counts ----------------
__global__ __launch_bounds__(1024) void k_scan(const int* __restrict__ cnt, int* __restrict__ offs,
                        int* __restrict__ cursor){
    int b = blockIdx.x, t = threadIdx.x;
    const int* c = cnt + (b<<15);
    int base = t*32;
    int pref[32];
    int s = 0;
    #pragma unroll
    for (int k4=0;k4<8;k4++){
        int4 q = *(const int4*)(c + base + k4*4);
        pref[k4*4+0]=s; s+=q.x;
        pref[k4*4+1]=s; s+=q.y;
        pref[k4*4+2]=s; s+=q.z;
        pref[k4*4+3]=s; s+=q.w;
    }
    int lane = t & 63, w = t >> 6;
    int inc = s;
    #pragma unroll
    for (int off=1; off<64; off<<=1){ int u = __shfl_up(inc, off); if (lane>=off) inc += u; }
    __shared__ int wsum[16];
    if (lane==63) wsum[w]=inc;
    __syncthreads();
    int wexcl=0;
    for (int i=0;i<w;i++) wexcl += wsum[i];
    int texcl = wexcl + inc - s;
    int* o = offs + (b<<15) + base;
    int* cu = cursor + (b<<15) + base;
    #pragma unroll
    for (int k=0;k<32;k++){ int v = texcl + pref[k]; o[k]=v; cu[k]=v; }
}

// ---------------- point_in conv1x1 via MFMA + inline FILL (slot assign + nrm scatter) ----------------
__global__ __launch_bounds__(256) void k_pin(const float* __restrict__ feats, const float* __restrict__ w_pin,
                      const int* __restrict__ pid, int* __restrict__ cursor,
                      int* __restrict__ slotmap, const float4* __restrict__ nrm,
                      float4* __restrict__ nrm_s,
                      ushort* __restrict__ ybuf, float* __restrict__ stats){
    __shared__ float sred[GRP*2];
    int t = threadIdx.x;
    if (t<GRP*2) sred[t]=0.f;
    __syncthreads();
    int l = t & 63, wv = t >> 6;
    int lc = l & 31, h = l >> 5;
    int p = blockIdx.x*128 + wv*32 + lc;
    int b = p >> 15, n = p & (NP-1);
    // fill: assign CSR slot (one point per (p, h==0) to avoid double-count)
    int slot;
    if (h==0){
        int v = pid[p];
        slot = atomicAdd(&cursor[(b<<15)+v], 1);
        slotmap[p] = slot;
        nrm_s[(b<<15)+slot] = nrm[p];
    }
    slot = __shfl(slot, lc, 64);          // broadcast from lane lc (h==0 half) to lane lc+32
    short8 aw[2][2];
    #pragma unroll
    for (int nt=0;nt<2;nt++)
    #pragma unroll
    for (int kc=0;kc<2;kc++){
        ushort tmp[8];
        #pragma unroll
        for (int j=0;j<8;j++) tmp[j]=f2bf(w_pin[(nt*32+lc)*CIN + kc*16 + h*8 + j]);
        aw[nt][kc]=*(short8*)tmp;
    }
    const float* fp = feats + (size_t)b*CIN*NP + n;
    short8 bf[2];
    #pragma unroll
    for (int kc=0;kc<2;kc++){
        ushort tmp[8];
        #pragma unroll
        for (int j=0;j<8;j++) tmp[j]=f2bf(fp[(size_t)(kc*16+h*8+j)*NP]);
        bf[kc]=*(short8*)tmp;
    }
    f32x16 acc0={}, acc1={};
    #pragma unroll
    for (int kc=0;kc<2;kc++){
        acc0 = __builtin_amdgcn_mfma_f32_32x32x16_bf16(aw[0][kc], bf[kc], acc0, 0,0,0);
        acc1 = __builtin_amdgcn_mfma_f32_32x32x16_bf16(aw[1][kc], bf[kc], acc1, 0,0,0);
    }
    ushort* yo = ybuf + ((size_t)(b<<15) + slot)*CO;
    float sg[8], qg[8];
    #pragma unroll
    for (int nt=0;nt<2;nt++){
        #pragma unroll
        for (int q=0;q<4;q++){
            ushort pk[4]; float s=0.f, qq=0.f;
            #pragma unroll
            for (int j=0;j<4;j++){
                float v = nt ? acc1[q*4+j] : acc0[q*4+j];
                pk[j]=f2bf(v); s+=v; qq+=v*v;
            }
            *(uint2*)(yo + nt*32 + q*8 + h*4) = *(uint2*)pk;
            sg[nt*4+q]=s; qg[nt*4+q]=qq;
        }
    }
    #pragma unroll
    for (int g=0;g<8;g++){
        float s=sg[g], q=qg[g];
        #pragma unroll
        for (int off=1; off<64; off<<=1){ s+=__shfl_xor(s,off); q+=__shfl_xor(q,off); }
        if (l==0){ atomicAdd(&sred[g*2],s); atomicAdd(&sred[g*2+1],q); }
    }
    __syncthreads();
    if (t<GRP){ atomicAdd(&stats[(b*GRP+t)*2], sred[t*2]); atomicAdd(&stats[(b*GRP+t)*2+1], sred[t*2+1]); }
}

// ---------------- gather per voxel over FULL padded volume (borders -> zero) ----------------
__global__ __launch_bounds__(256) void k_gather_pad(const ushort* __restrict__ ybuf, const int* __restrict__ offs,
                             const float* __restrict__ stats,
                             const float* __restrict__ gamma, const float* __restrict__ beta,
                             ushort* __restrict__ P){
    int i = blockIdx.x*256 + threadIdx.x;   // RB*CPB
    int b = i / CPB;
    int r = i - b*CPB;
    ushort* dst = P + (size_t)b*PVOL + (size_t)r*8;
    int pvox = r >> 3, c8 = r & 7;
    int pu = pvox / (PR*PR);
    int rem = pvox - pu*PR*PR;
    int pv = rem / PR;
    int pw = rem - pv*PR;
    if (pu==0 || pu==PR-1 || pv==0 || pv==PR-1 || pw==0 || pw==PR-1){
        uint4 z = {0,0,0,0};
        *(uint4*)dst = z;
        return;
    }
    int vox = ((pu-1)*RR + (pv-1))*RR + (pw-1);
    float s = stats[(b*GRP+c8)*2], qq = stats[(b*GRP+c8)*2+1];
    float m = s/GN_CNT;
    float inv = rsqrtf(qq/GN_CNT - m*m + 1e-5f);
    float ga[8], be[8];
    #pragma unroll
    for (int k=0;k<8;k++){ ga[k]=gamma[c8*8+k]*inv; be[k]=beta[c8*8+k]-m*ga[k]; }
    int o0 = offs[(b<<15)+vox];
    int o1 = (vox==NVOX-1) ? NP : offs[(b<<15)+vox+1];
    float acc[8];
    #pragma unroll
    for (int k=0;k<8;k++) acc[k]=0.f;
    for (int j=o0; j<o1; j++){
        uint4 raw = *(const uint4*)(ybuf + ((size_t)((b<<15)+j))*CO + c8*8);
        ushort* us = (ushort*)&raw;
        #pragma unroll
        for (int k=0;k<8;k++){
            float x = bf2f(us[k])*ga[k] + be[k];
            acc[k] += silu_f(x);
        }
    }
    float rc = (o1>o0) ? 1.f/(float)(o1-o0) : 0.f;
    ushort out[8];
    #pragma unroll
    for (int k=0;k<8;k++) out[k]=f2bf(acc[k]*rc);
    *(uint4*)dst = *(uint4*)out;
}

// ---------------- conv1: MFMA conv3d from padded Pvol (R9-proven) + setprio ----------------
__global__ __launch_bounds__(256, 2) void k_conv1(const ushort* __restrict__ P,
                        const short* __restrict__ wpack,
                        ushort* __restrict__ outv, float* __restrict__ stats){
    __shared__ __align__(16) char lds[10*4352 + 24576];   // 43520 act + 24576 w = 68096 B
    char* wlds = lds + 10*4352;
    int t = threadIdx.x;
    int blk = blockIdx.x;                 // ((b*32+u)*4 + vt)
    int vt = blk & 3;
    int u  = (blk >> 2) & 31;
    int b  = blk >> 7;
    int v0 = vt*8;

    int l  = t & 63;
    int wv = t >> 6;
    int lr = l & 31;
    int lh = l >> 5;

    f32x16 acc00 = {}, acc01 = {}, acc10 = {}, acc11 = {};

    for (int dz = 0; dz < 3; dz++){
        for (int i = t; i < 2720; i += 256){
            int r = i / 272;
            int chunk = i - r*272;
            size_t src = (size_t)b*PVOL + (size_t)(u+dz)*PSLICE + (size_t)(v0+r)*PROW + (size_t)chunk*8;
            uint4 val = *(const uint4*)(P + src);
            int vx = chunk >> 3;
            int colb = (chunk & 7) << 4;
            *(uint4*)(lds + r*4352 + vx*128 + (colb ^ ((vx&7)<<4))) = val;
        }
        for (int dy = 0; dy < 3; dy++){
            const uint4* wsrc = (const uint4*)(wpack + (size_t)(dz*9 + dy*3)*4096);
            uint4* wdst = (uint4*)wlds;
            #pragma unroll
            for (int i=0;i<6;i++) wdst[t + i*256] = wsrc[t + i*256];
            __syncthreads();
            __builtin_amdgcn_s_setprio(1);
            #pragma unroll
            for (int dx = 0; dx < 3; dx++){
                int vx = lr + dx;
                int sw = (vx & 7) << 4;
                int ra = (2*wv + dy)*4352 + vx*128;
                int wb = dx*8192 + l*16;
                #pragma unroll
                for (int kc = 0; kc < 4; kc++){
                    short8 bw0 = *(const short8*)(wlds + wb + kc*2048);
                    short8 bw1 = *(const short8*)(wlds + wb + kc*2048 + 1024);
                    int col = (kc*32 + lh*16) ^ sw;
                    short8 av0 = *(const short8*)(lds + ra + col);
                    short8 av1 = *(const short8*)(lds + ra + 4352 + col);
                    acc00 = __builtin_amdgcn_mfma_f32_32x32x16_bf16(av0, bw0, acc00, 0, 0, 0);
                    acc01 = __builtin_amdgcn_mfma_f32_32x32x16_bf16(av0, bw1, acc01, 0, 0, 0);
                    acc10 = __builtin_amdgcn_mfma_f32_32x32x16_bf16(av1, bw0, acc10, 0, 0, 0);
                    acc11 = __builtin_amdgcn_mfma_f32_32x32x16_bf16(av1, bw1, acc11, 0, 0, 0);
                }
            }
            __builtin_amdgcn_s_setprio(0);
            __syncthreads();
        }
    }

    ushort* ob = outv;
    float s0 = 0.f, q0 = 0.f, s1 = 0.f, q1 = 0.f;
    size_t vrow0 = ((size_t)(b*32 + u)*32 + v0 + 2*wv);
    #pragma unroll
    for (int reg = 0; reg < 16; reg++){
        int x = (reg&3) + 8*(reg>>2) + 4*lh;
        float a, c;
        a = acc00[reg]; c = acc01[reg];
        s0 += a; q0 += a*a; s1 += c; q1 += c*c;
        ob[(vrow0*32 + x)*CO + lr]      = f2bf(a);
        ob[(vrow0*32 + x)*CO + 32 + lr] = f2bf(c);
        a = acc10[reg]; c = acc11[reg];
        s0 += a; q0 += a*a; s1 += c; q1 += c*c;
        ob[((vrow0+1)*32 + x)*CO + lr]      = f2bf(a);
        ob[((vrow0+1)*32 + x)*CO + 32 + lr] = f2bf(c);
    }
    #pragma unroll
    for (int off : {1,2,4,32}){
        s0 += __shfl_xor(s0, off); q0 += __shfl_xor(q0, off);
        s1 += __shfl_xor(s1, off); q1 += __shfl_xor(q1, off);
    }
    if (lh==0 && (lr&7)==0){
        int g0 = lr>>3;
        atomicAdd(&stats[(b*GRP+g0)*2],     s0);
        atomicAdd(&stats[(b*GRP+g0)*2+1],   q0);
        atomicAdd(&stats[(b*GRP+4+g0)*2],   s1);
        atomicAdd(&stats[(b*GRP+4+g0)*2+1], q1);
    }
}

// ---------------- conv2: GN(st1)+SiLU fused into staging (zero-pad via bounds) + setprio ----------------
__global__ __launch_bounds__(256, 2) void k_conv2(const ushort* __restrict__ in,
                        const short* __restrict__ wpack,
                        const float* __restrict__ gst, const float* __restrict__ gg,
                        const float* __restrict__ gb,
                        ushort* __restrict__ outv, float* __restrict__ stats){
    __shared__ __align__(16) char lds[10*4352 + 24576];
    char* wlds = lds + 10*4352;
    int t = threadIdx.x;
    int blk = blockIdx.x;
    int vt = blk & 3;
    int u  = (blk >> 2) & 31;
    int b  = blk >> 7;
    int v0 = vt*8;

    int l  = t & 63;
    int wv = t >> 6;
    int lr = l & 31;
    int lh = l >> 5;

    float gm[8], gi[8];
    #pragma unroll
    for (int g=0; g<8; g++){
        float m = gst[(b*GRP+g)*2]/GN_CNT;
        gm[g] = m;
        gi[g] = rsqrtf(gst[(b*GRP+g)*2+1]/GN_CNT - m*m + 1e-5f);
    }

    f32x16 acc00 = {}, acc01 = {}, acc10 = {}, acc11 = {};

    for (int dz = 0; dz < 3; dz++){
        for (int i = t; i < 2720; i += 256){
            int r = i / 272;
            int chunk = i - r*272;
            int vx = chunk >> 3;
            int c8 = chunk & 7;
            uint4 val = make_uint4(0,0,0,0);
            int au = u + dz - 1, av = v0 + r - 1, ax = vx - 1;
            if ((unsigned)au < 32u && (unsigned)av < 32u && (unsigned)ax < 32u){
                uint4 rv = *(const uint4*)(in + ((size_t)(((b*32+au)*32+av)*32+ax))*CO + c8*8);
                float m = gm[c8], iv = gi[c8];
                ushort* us = (ushort*)&rv;
                ushort o8[8];
                #pragma unroll
                for (int j=0;j<8;j++){
                    int c = c8*8+j;
                    float x = (bf2f(us[j]) - m)*iv*gg[c] + gb[c];
                    o8[j] = f2bf(silu_f(x));
                }
                val = *(uint4*)o8;
            }
            *(uint4*)(lds + r*4352 + vx*128 + ((c8<<4) ^ ((vx&7)<<4))) = val;
        }
        for (int dy = 0; dy < 3; dy++){
            const uint4* wsrc = (const uint4*)(wpack + (size_t)(dz*9 + dy*3)*4096);
            uint4* wdst = (uint4*)wlds;
            #pragma unroll
            for (int i=0;i<6;i++) wdst[t + i*256] = wsrc[t + i*256];
            __syncthreads();
            __builtin_amdgcn_s_setprio(1);
            #pragma unroll
            for (int dx = 0; dx < 3; dx++){
                int vx = lr + dx;
                int sw = (vx & 7) << 4;
                int ra = (2*wv + dy)*4352 + vx*128;
                int wb = dx*8192 + l*16;
                #pragma unroll
                for (int kc = 0; kc < 4; kc++){
                    short8 bw0 = *(const short8*)(wlds + wb + kc*2048);
                    short8 bw1 = *(const short8*)(wlds + wb + kc*2048 + 1024);
                    int col = (kc*32 + lh*16) ^ sw;
                    short8 av0 = *(const short8*)(lds + ra + col);
                    short8 av1 = *(const short8*)(lds + ra + 4352 + col);
                    acc00 = __builtin_amdgcn_mfma_f32_32x32x16_bf16(av0, bw0, acc00, 0, 0, 0);
                    acc01 = __builtin_amdgcn_mfma_f32_32x32x16_bf16(av0, bw1, acc01, 0, 0, 0);
                    acc10 = __builtin_amdgcn_mfma_f32_32x32x16_bf16(av1, bw0, acc10, 0, 0, 0);
                    acc11 = __builtin_amdgcn_mfma_f32_32x32x16_bf16(av1, bw1, acc11, 0, 0, 0);
                }
            }
            __builtin_amdgcn_s_setprio(0);
            __syncthreads();
        }
    }

    ushort* ob = outv;
    float s0 = 0.f, q0 = 0.f, s1 = 0.f, q1 = 0.f;
    size_t vrow0 = ((size_t)(b*32 + u)*32 + v0 + 2*wv);
    #pragma unroll
    for (int reg = 0; reg < 16; reg++){
        int x = (reg&3) + 8*(reg>>2) + 4*lh;
        float a, c;
        a = acc00[reg]; c = acc01[reg];
        s0 += a; q0 += a*a; s1 += c; q1 += c*c;
        ob[(vrow0*32 + x)*CO + lr]      = f2bf(a);
        ob[(vrow0*32 + x)*CO + 32 + lr] = f2bf(c);
        a = acc10[reg]; c = acc11[reg];
        s0 += a; q0 += a*a; s1 += c; q1 += c*c;
        ob[((vrow0+1)*32 + x)*CO + lr]      = f2bf(a);
        ob[((vrow0+1)*32 + x)*CO + 32 + lr] = f2bf(c);
    }
    #pragma unroll
    for (int off : {1,2,4,32}){
        s0 += __shfl_xor(s0, off); q0 += __shfl_xor(q0, off);
        s1 += __shfl_xor(s1, off); q1 += __shfl_xor(q1, off);
    }
    if (lh==0 && (lr&7)==0){
        int g0 = lr>>3;
        atomicAdd(&stats[(b*GRP+g0)*2],     s0);
        atomicAdd(&stats[(b*GRP+g0)*2+1],   q0);
        atomicAdd(&stats[(b*GRP+4+g0)*2],   s1);
        atomicAdd(&stats[(b*GRP+4+g0)*2+1], q1);
    }
}

// ---------------- devoxelize in CSR-SORTED order (+fused GN+SiLU of conv2) + fuse conv1x1 + stats ----------------
__global__ __launch_bounds__(256) void k_devox_fuse(const ushort* __restrict__ vox_,
                             const float4* __restrict__ nrm_s, const float* __restrict__ wf,
                             const float* __restrict__ st2, const float* __restrict__ g_v2,
                             const float* __restrict__ b_v2,
                             ushort* __restrict__ obuf, float* __restrict__ stats){
    __shared__ float sred[GRP*2];
    int t = threadIdx.x;
    if (t<GRP*2) sred[t]=0.f;
    __syncthreads();
    int l = t & 63, wv = t >> 6;
    int lc = l & 31, h = l >> 5;
    int j_ = blockIdx.x*128 + wv*32 + lc;      // sorted slot index
    int b = j_ >> 15;
    short8 aw[2][4];
    #pragma unroll
    for (int nt=0;nt<2;nt++)
    #pragma unroll
    for (int kc=0;kc<4;kc++){
        ushort tmp[8];
        #pragma unroll
        for (int j=0;j<8;j++) tmp[j]=f2bf(wf[(nt*32+lc)*CO + kc*16 + h*8 + j]);
        aw[nt][kc]=*(short8*)tmp;
    }
    float ga[4][8], be[4][8];
    #pragma unroll
    for (int kc=0;kc<4;kc++){
        int g = kc*2 + h;
        float s = st2[(b*GRP+g)*2], qq = st2[(b*GRP+g)*2+1];
        float m = s/GN_CNT;
        float inv = rsqrtf(qq/GN_CNT - m*m + 1e-5f);
        #pragma unroll
        for (int j=0;j<8;j++){
            int c = kc*16 + h*8 + j;
            ga[kc][j] = g_v2[c]*inv;
            be[kc][j] = b_v2[c] - m*ga[kc][j];
        }
    }
    float4 nr4 = nrm_s[j_];
    float f3[3] = {nr4.x, nr4.y, nr4.z};
    float fr[3]; int x0[3];
    #pragma unroll
    for(int d=0;d<3;d++){
        float fl = floorf(f3[d]);
        x0[d]=(int)fl; fr[d]=f3[d]-fl;
    }
    float dev[4][8] = {};
    const ushort* vb = vox_ + (size_t)b*NVOX*CO;
    #pragma unroll
    for (int k=0;k<8;k++){
        int d0=(k>>2)&1, d1=(k>>1)&1, d2=k&1;
        int i0=min(x0[0]+d0,RR-1), i1=min(x0[1]+d1,RR-1), i2=min(x0[2]+d2,RR-1);
        float w = (d0?fr[0]:1.f-fr[0])*(d1?fr[1]:1.f-fr[1])*(d2?fr[2]:1.f-fr[2]);
        const ushort* vp = vb + (size_t)((i0*RR+i1)*RR+i2)*CO + h*8;
        #pragma unroll
        for (int kc=0;kc<4;kc++){
            uint4 rv = *(const uint4*)(vp + kc*16);
            ushort* us = (ushort*)&rv;
            #pragma unroll
            for (int j=0;j<8;j++){
                float x = bf2f(us[j])*ga[kc][j] + be[kc][j];
                dev[kc][j] += w * silu_f(x);
            }
        }
    }
    short8 bf[4];
    #pragma unroll
    for (int kc=0;kc<4;kc++){
        ushort tmp[8];
        #pragma unroll
        for (int j=0;j<8;j++) tmp[j]=f2bf(dev[kc][j]);
        bf[kc]=*(short8*)tmp;
    }
    f32x16 acc0={}, acc1={};
    #pragma unroll
    for (int kc=0;kc<4;kc++){
        acc0 = __builtin_amdgcn_mfma_f32_32x32x16_bf16(aw[0][kc], bf[kc], acc0, 0,0,0);
        acc1 = __builtin_amdgcn_mfma_f32_32x32x16_bf16(aw[1][kc], bf[kc], acc1, 0,0,0);
    }
    ushort* op = obuf + (size_t)j_*CO;
    float sg[8], qg[8];
    #pragma unroll
    for (int nt=0;nt<2;nt++){
        #pragma unroll
        for (int q=0;q<4;q++){
            ushort pk[4]; float s=0.f, qq=0.f;
            #pragma unroll
            for (int j=0;j<4;j++){
                float v = nt ? acc1[q*4+j] : acc0[q*4+j];
                pk[j]=f2bf(v); s+=v; qq+=v*v;
            }
            *(uint2*)(op + nt*32 + q*8 + h*4) = *(uint2*)pk;
            sg[nt*4+q]=s; qg[nt*4+q]=qq;
        }
    }
    #pragma unroll
    for (int g=0;g<8;g++){
        float s=sg[g], q=qg[g];
        #pragma unroll
        for (int off=1; off<64; off<<=1){ s+=__shfl_xor(s,off); q+=__shfl_xor(q,off); }
        if (l==0){ atomicAdd(&sred[g*2],s); atomicAdd(&sred[g*2+1],q); }
    }
    __syncthreads();
    if (t<GRP){ atomicAdd(&stats[(b*GRP+t)*2], sred[t*2]); atomicAdd(&stats[(b*GRP+t)*2+1], sred[t*2+1]); }
}

// ---------------- final: GN+SiLU + MFMA skip conv + AdaIN, write (B,C,N) ----------------
__global__ __launch_bounds__(256) void k_final(const ushort* __restrict__ obuf, const int* __restrict__ slotmap,
                        const float* __restrict__ stats,
                        const float* __restrict__ gamma, const float* __restrict__ beta,
                        const float* __restrict__ feats, const float* __restrict__ wskip,
                        const float* __restrict__ ada_s, const float* __restrict__ ada_b,
                        float* __restrict__ out){
    int t = threadIdx.x;
    int l = t & 63, wv = t >> 6;
    int lc = l & 31, h = l >> 5;
    int p = blockIdx.x*128 + wv*32 + lc;
    int b = p >> 15, n = p & (NP-1);
    short8 aw[2][2];
    #pragma unroll
    for (int nt=0;nt<2;nt++)
    #pragma unroll
    for (int kc=0;kc<2;kc++){
        ushort tmp[8];
        #pragma unroll
        for (int j=0;j<8;j++) tmp[j]=f2bf(wskip[(nt*32+lc)*CIN + kc*16 + h*8 + j]);
        aw[nt][kc]=*(short8*)tmp;
    }
    const float* fp = feats + (size_t)b*CIN*NP + n;
    short8 bf[2];
    #pragma unroll
    for (int kc=0;kc<2;kc++){
        ushort tmp[8];
        #pragma unroll
        for (int j=0;j<8;j++) tmp[j]=f2bf(fp[(size_t)(kc*16+h*8+j)*NP]);
        bf[kc]=*(short8*)tmp;
    }
    f32x16 acc0={}, acc1={};
    #pragma unroll
    for (int kc=0;kc<2;kc++){
        acc0 = __builtin_amdgcn_mfma_f32_32x32x16_bf16(aw[0][kc], bf[kc], acc0, 0,0,0);
        acc1 = __builtin_amdgcn_mfma_f32_32x32x16_bf16(aw[1][kc], bf[kc], acc1, 0,0,0);
    }
    float mean[GRP], inv[GRP];
    #pragma unroll
    for (int g=0; g<GRP; g++){
        float s=stats[(b*GRP+g)*2], q=stats[(b*GRP+g)*2+1];
        float m=s/GN_CNT;
        mean[g]=m; inv[g]=rsqrtf(q/GN_CNT - m*m + 1e-5f);
    }
    int slot = slotmap[p];
    const ushort* ip = obuf + ((size_t)(b<<15) + slot)*CO;
    float* op = out + (size_t)b*CO*NP + n;
    #pragma unroll
    for (int nt=0;nt<2;nt++){
        #pragma unroll
        for (int q=0;q<4;q++){
            uint2 raw = *(const uint2*)(ip + nt*32 + q*8 + h*4);
            ushort* us = (ushort*)&raw;
            int g = nt*4 + q;
            #pragma unroll
            for (int j=0;j<4;j++){
                int oc = nt*32 + q*8 + h*4 + j;
                float u = (bf2f(us[j]) - mean[g])*inv[g]*gamma[oc] + beta[oc];
                u = silu_f(u);
                float sk = nt ? acc1[q*4+j] : acc0[q*4+j];
                float s = ada_s[b*CO+oc], bb = ada_b[b*CO+oc];
                op[(size_t)oc*NP] = (u+sk)*(1.f+s)+bb;
            }
        }
    }
}

extern "C" void kernel_launch(void* const* d_in, const int* in_sizes, int n_in,
                              void* d_out, int out_size, void* d_ws, size_t ws_size,
                              hipStream_t stream){
    const float* feats =(const float*)d_in[0];
    const float* coords=(const float*)d_in[1];
    const float* style =(const float*)d_in[2];
    const float* w_pin =(const float*)d_in[3];
    const float* g_pin =(const float*)d_in[4];
    const float* b_pin =(const float*)d_in[5];
    const float* w_v1  =(const float*)d_in[6];
    const float* g_v1  =(const float*)d_in[7];
    const float* b_v1  =(const float*)d_in[8];
    const float* w_v2  =(const float*)d_in[9];
    const float* g_v2  =(const float*)d_in[10];
    const float* b_v2  =(const float*)d_in[11];
    const float* w_fuse=(const float*)d_in[12];
    const float* g_f   =(const float*)d_in[13];
    const float* b_f   =(const float*)d_in[14];
    const float* w_skip=(const float*)d_in[15];
    const float* w_as  =(const float*)d_in[16];
    const float* b_as  =(const float*)d_in[17];
    const float* w_ab  =(const float*)d_in[18];
    const float* b_ab  =(const float*)d_in[19];
    float* out=(float*)d_out;
    char* ws =(char*)d_ws;

    // workspace layout (bytes)
    ushort* ybuf  = (ushort*)ws;                            // 16.7 MB (aliased later by obuf)
    ushort* Pvol  = (ushort*)(ws + 16777216);               // 20.1 MB (reused as conv2 out)
    ushort* raw   = (ushort*)(ws + 16777216 + 20123648);    // 16.7 MB
    char*   small = ws + 16777216 + 20123648 + 16777216;
    float* stats  = (float*)small;                          // 256 floats
    float* vmm    = stats + 256;                            // 24
    float* ada_s  = vmm + 24;                               // 256
    float* ada_b  = ada_s + RB*CO;                          // 256
    short* wp1    = (short*)(ada_b + RB*CO);                // 110592 shorts
    short* wp2    = wp1 + 27*4*2*64*8;                      // 110592 shorts
    int*   pid    = (int*)(wp2 + 27*4*2*64*8);              // RB*NP
    int*   cnt    = pid + RB*NP;                            // RB*NVOX
    int*   offs   = cnt + RB*NVOX;                          // RB*NVOX
    int*   cursor = offs + RB*NVOX;                         // RB*NVOX
    int*   slotmap= cursor + RB*NVOX;                       // RB*NP
    float4* nrm4  = (float4*)(slotmap + RB*NP);             // RB*NP float4
    float4* nrm_s = nrm4 + RB*NP;                           // RB*NP float4
    ushort* vox2  = Pvol;                                   // conv2 output (unpadded 16.7 MB)
    ushort* obuf  = ybuf;                                   // reuse after gather

    float* st0 = stats;
    float* st1 = stats + 64;
    float* st2 = stats + 128;
    float* st3 = stats + 192;

    k_prep<<<625,256,0,stream>>>(w_v1,w_v2,wp1,wp2,style,w_as,b_as,w_ab,b_ab,
                                 ada_s,ada_b,stats,coords,vmm,cnt);
    k_count<<<RB*NP/256,256,0,stream>>>(coords,vmm,pid,cnt,nrm4);
    k_scan<<<RB,1024,0,stream>>>(cnt,offs,cursor);
    k_pin<<<RB*NP/128,256,0,stream>>>(feats,w_pin,pid,cursor,slotmap,nrm4,nrm_s,ybuf,st0);
    k_gather_pad<<<RB*CPB/256,256,0,stream>>>(ybuf,offs,st0,g_pin,b_pin,Pvol);

    k_conv1<<<RB*RR*4,256,0,stream>>>(Pvol, wp1, raw, st1);
    k_conv2<<<RB*RR*4,256,0,stream>>>(raw, wp2, st1, g_v1, b_v1, vox2, st2);

    k_devox_fuse<<<RB*NP/128,256,0,stream>>>(vox2, nrm_s, w_fuse,
                                             st2, g_v2, b_v2, obuf, st3);
    k_final<<<RB*NP/128,256,0,stream>>>(obuf, slotmap, st3, g_f, b_f, feats, w_skip, ada_s, ada_b, out);
}